// Round 1
// baseline (519.366 us; speedup 1.0000x reference)
//
#include <hip/hip_runtime.h>

// DeepSeek MoE (N=2048, D=768, I=3072, E=8, K=2 + shared expert), fp32 in/out,
// bf16 MFMA compute. Sparse routed experts via counting-sort + grouped GEMM.
//
// Pipeline: tcast (weights -> bf16 B^T) x6 | cast_x | gate_topk | route_build |
//           gather | gemm_act (fused W1/W3 + clamp/silu, shared+routed in one
//           launch) | gemm_out (W2) | combine.

#define D_ 768
#define I_ 3072
#define E_ 8
#define NTOK 2048
#define NPMAX 5120          // 4096 pairs + worst-case 128-padding per expert
#define MAXTILES 40         // sum ceil(c_e/128) <= 39
#define NSHT 16             // shared-expert M tiles: 2048/128

typedef __bf16 bf16x8 __attribute__((ext_vector_type(8)));
typedef float floatx4 __attribute__((ext_vector_type(4)));

__device__ __forceinline__ unsigned short f2b(float f) {
    unsigned int u = __float_as_uint(f);
    u += 0x7fffu + ((u >> 16) & 1u);          // RNE to bf16
    return (unsigned short)(u >> 16);
}

// ---------------- cast / transpose ----------------

// src fp32 [batch][R][C] -> dst bf16 [batch][C][R]
__global__ void tcast_kernel(const float* __restrict__ src,
                             unsigned short* __restrict__ dst, int R, int C) {
    __shared__ float t[32][33];
    const float* s = src + (size_t)blockIdx.z * R * C;
    unsigned short* d = dst + (size_t)blockIdx.z * R * C;
    int c0 = blockIdx.x * 32, r0 = blockIdx.y * 32;
    int tx = threadIdx.x & 31, ty = threadIdx.x >> 5;   // ty: 0..7
#pragma unroll
    for (int j = 0; j < 4; j++) {
        int r = ty + j * 8;
        t[r][tx] = s[(size_t)(r0 + r) * C + c0 + tx];
    }
    __syncthreads();
#pragma unroll
    for (int j = 0; j < 4; j++) {
        int c = ty + j * 8;
        d[(size_t)(c0 + c) * R + r0 + tx] = f2b(t[tx][c]);
    }
}

__global__ void cast_x_kernel(const float* __restrict__ x,
                              unsigned short* __restrict__ xb) {
    int gid = blockIdx.x * 256 + threadIdx.x;   // one float4 each, exact grid
    float4 v = *(const float4*)(x + (size_t)gid * 4);
    ushort4 o;
    o.x = f2b(v.x); o.y = f2b(v.y); o.z = f2b(v.z); o.w = f2b(v.w);
    *(ushort4*)(xb + (size_t)gid * 4) = o;
}

// ---------------- gating ----------------

__global__ void gate_topk_kernel(const float* __restrict__ x,
                                 const float* __restrict__ gw,
                                 const float* __restrict__ gb,
                                 int* __restrict__ idx, float* __restrict__ wts) {
    int t = blockIdx.x * 4 + (threadIdx.x >> 6);   // one wave per token
    int lane = threadIdx.x & 63;
    float z[E_];
#pragma unroll
    for (int e = 0; e < E_; e++) z[e] = 0.f;
    const float* xr = x + (size_t)t * D_;
    for (int j = lane; j < D_; j += 64) {
        float xv = xr[j];
        const float* g = gw + (size_t)j * E_;
#pragma unroll
        for (int e = 0; e < E_; e++) z[e] += xv * g[e];
    }
#pragma unroll
    for (int off = 32; off > 0; off >>= 1)
#pragma unroll
        for (int e = 0; e < E_; e++) z[e] += __shfl_down(z[e], off, 64);
    if (lane == 0) {
        float s[E_], r[E_];
#pragma unroll
        for (int e = 0; e < E_; e++) {
            float zz = z[e];
            float sp = zz > 0.f ? zz + log1pf(expf(-zz)) : log1pf(expf(zz));
            s[e] = sqrtf(sp);
            r[e] = s[e] + gb[e];   // bias only for selection
        }
        int i0 = 0;
        for (int e = 1; e < E_; e++) if (r[e] > r[i0]) i0 = e;   // ties -> low idx
        int i1 = (i0 == 0) ? 1 : 0;
        for (int e = 0; e < E_; e++) if (e != i0 && r[e] > r[i1]) i1 = e;
        float w0 = s[i0], w1 = s[i1];
        float inv = 1.f / fmaxf(w0 + w1, 1e-6f);
        idx[2 * t] = i0; idx[2 * t + 1] = i1;
        wts[2 * t] = w0 * inv; wts[2 * t + 1] = w1 * inv;
    }
}

// ---------------- routing build (single block) ----------------

__global__ void route_build_kernel(const int* __restrict__ idx,
                                   const float* __restrict__ wts,
                                   int* __restrict__ pair_token,
                                   float* __restrict__ pair_w,
                                   int* __restrict__ pos_of,
                                   int* __restrict__ tiles) {
    __shared__ int cnt[E_], seg[E_], cur[E_];
    int tid = threadIdx.x;
    if (tid < E_) { cnt[tid] = 0; cur[tid] = 0; }
    __syncthreads();
    for (int p = tid; p < NTOK * 2; p += 256) atomicAdd(&cnt[idx[p]], 1);
    __syncthreads();
    if (tid == 0) {
        int off = 0, nt = 0;
        for (int e = 0; e < E_; e++) {
            seg[e] = off;
            int te = (cnt[e] + 127) >> 7;
            for (int j = 0; j < te; j++) {
                tiles[nt * 2] = e; tiles[nt * 2 + 1] = off + j * 128; nt++;
            }
            off += te * 128;
        }
        for (; nt < MAXTILES; nt++) { tiles[nt * 2] = -1; tiles[nt * 2 + 1] = 0; }
    }
    for (int p = tid; p < NPMAX; p += 256) pair_token[p] = -1;
    __syncthreads();
    for (int p = tid; p < NTOK * 2; p += 256) {
        int e = idx[p];
        int r = atomicAdd(&cur[e], 1);
        int pos = seg[e] + r;
        pair_token[pos] = p >> 1;
        pair_w[pos] = wts[p];
        pos_of[p] = pos;
    }
}

__global__ void gather_kernel(const unsigned short* __restrict__ xb,
                              const int* __restrict__ pair_token,
                              unsigned short* __restrict__ xg) {
    int gid = blockIdx.x * 256 + threadIdx.x;   // 8 bf16 each, exact grid
    int p = gid / (D_ / 8);
    int j = (gid % (D_ / 8)) * 8;
    int t = pair_token[p];
    int4 v = make_int4(0, 0, 0, 0);             // pad rows -> zeros
    if (t >= 0) v = *(const int4*)(xb + (size_t)t * D_ + j);
    *(int4*)(xg + (size_t)p * D_ + j) = v;
}

// ---------------- GEMM 1: fused gate/up + activation ----------------
// BM=128, BN=64, BK=32; 4 waves, each 64x32 (4x2 MFMA tiles), both W1 and W3.
// A: [rows][768] bf16. B^T: [I][768] bf16. Out: act bf16 [rows][I].

__launch_bounds__(256)
__global__ void gemm_act_kernel(const unsigned short* __restrict__ xb,
                                const unsigned short* __restrict__ xg,
                                const unsigned short* __restrict__ w1sb,
                                const unsigned short* __restrict__ w3sb,
                                const unsigned short* __restrict__ w1b,
                                const unsigned short* __restrict__ w3b,
                                const int* __restrict__ tiles,
                                unsigned short* __restrict__ act_s,
                                unsigned short* __restrict__ act_r) {
    __shared__ __align__(16) unsigned short As[128 * 40];   // +8 pad: 2-way max
    __shared__ __align__(16) unsigned short Bs1[64 * 40];
    __shared__ __align__(16) unsigned short Bs3[64 * 40];

    int mt = blockIdx.y;
    const unsigned short *A, *B1, *B3;
    unsigned short* C;
    int m0;
    if (mt < NSHT) {
        A = xb; B1 = w1sb; B3 = w3sb; C = act_s; m0 = mt * 128;
    } else {
        int e = tiles[(mt - NSHT) * 2];
        if (e < 0) return;
        m0 = tiles[(mt - NSHT) * 2 + 1];
        A = xg; B1 = w1b + (size_t)e * I_ * D_; B3 = w3b + (size_t)e * I_ * D_;
        C = act_r;
    }
    int n0 = blockIdx.x * 64;
    int tid = threadIdx.x;
    int lane = tid & 63, wave = tid >> 6;
    int wm = (wave & 1) * 64, wn = (wave >> 1) * 32;
    int l15 = lane & 15, quad = lane >> 4;

    int arow0 = tid >> 2, cc0 = (tid & 3) * 8;
    int arow1 = arow0 + 64;
    int brow = tid >> 2;

    floatx4 acc1[4][2] = {}; floatx4 acc3[4][2] = {};

    for (int k0 = 0; k0 < D_; k0 += 32) {
        __syncthreads();
        int4 va0 = *(const int4*)(A + (size_t)(m0 + arow0) * D_ + k0 + cc0);
        int4 va1 = *(const int4*)(A + (size_t)(m0 + arow1) * D_ + k0 + cc0);
        int4 vb1 = *(const int4*)(B1 + (size_t)(n0 + brow) * D_ + k0 + cc0);
        int4 vb3 = *(const int4*)(B3 + (size_t)(n0 + brow) * D_ + k0 + cc0);
        *(int4*)(As + arow0 * 40 + cc0) = va0;
        *(int4*)(As + arow1 * 40 + cc0) = va1;
        *(int4*)(Bs1 + brow * 40 + cc0) = vb1;
        *(int4*)(Bs3 + brow * 40 + cc0) = vb3;
        __syncthreads();

        bf16x8 af[4], b1f[2], b3f[2];
#pragma unroll
        for (int mi = 0; mi < 4; mi++)
            af[mi] = *(const bf16x8*)(As + (wm + mi * 16 + l15) * 40 + quad * 8);
#pragma unroll
        for (int ni = 0; ni < 2; ni++) {
            b1f[ni] = *(const bf16x8*)(Bs1 + (wn + ni * 16 + l15) * 40 + quad * 8);
            b3f[ni] = *(const bf16x8*)(Bs3 + (wn + ni * 16 + l15) * 40 + quad * 8);
        }
#pragma unroll
        for (int mi = 0; mi < 4; mi++)
#pragma unroll
            for (int ni = 0; ni < 2; ni++) {
                acc1[mi][ni] = __builtin_amdgcn_mfma_f32_16x16x32_bf16(
                    af[mi], b1f[ni], acc1[mi][ni], 0, 0, 0);
                acc3[mi][ni] = __builtin_amdgcn_mfma_f32_16x16x32_bf16(
                    af[mi], b3f[ni], acc3[mi][ni], 0, 0, 0);
            }
    }

#pragma unroll
    for (int mi = 0; mi < 4; mi++)
#pragma unroll
        for (int ni = 0; ni < 2; ni++) {
            int col = n0 + wn + ni * 16 + l15;
#pragma unroll
            for (int r = 0; r < 4; r++) {
                int row = m0 + wm + mi * 16 + quad * 4 + r;   // C/D: row=quad*4+r
                float g = fminf(acc1[mi][ni][r], 10.f);
                float u = fminf(fmaxf(acc3[mi][ni][r], -10.f), 10.f);
                float a = g / (1.f + __expf(-g)) * u;          // silu(g)*u
                C[(size_t)row * I_ + col] = f2b(a);
            }
        }
}

// ---------------- GEMM 2: act @ W2 ----------------
// A: act bf16 [rows][3072]. B^T: w2b [768][3072] bf16. Out: fp32 [rows][768].

__launch_bounds__(256)
__global__ void gemm_out_kernel(const unsigned short* __restrict__ act_s,
                                const unsigned short* __restrict__ act_r,
                                const unsigned short* __restrict__ w2sb,
                                const unsigned short* __restrict__ w2b,
                                const int* __restrict__ tiles,
                                float* __restrict__ y_s, float* __restrict__ ro) {
    __shared__ __align__(16) unsigned short As[128 * 40];
    __shared__ __align__(16) unsigned short Bs[64 * 40];

    int mt = blockIdx.y;
    const unsigned short *A, *B;
    float* C;
    int m0;
    if (mt < NSHT) {
        A = act_s; B = w2sb; C = y_s; m0 = mt * 128;
    } else {
        int e = tiles[(mt - NSHT) * 2];
        if (e < 0) return;
        m0 = tiles[(mt - NSHT) * 2 + 1];
        A = act_r; B = w2b + (size_t)e * I_ * D_; C = ro;
    }
    int n0 = blockIdx.x * 64;
    int tid = threadIdx.x;
    int lane = tid & 63, wave = tid >> 6;
    int wm = (wave & 1) * 64, wn = (wave >> 1) * 32;
    int l15 = lane & 15, quad = lane >> 4;

    int arow0 = tid >> 2, cc0 = (tid & 3) * 8;
    int arow1 = arow0 + 64;
    int brow = tid >> 2;

    floatx4 acc[4][2] = {};

    for (int k0 = 0; k0 < I_; k0 += 32) {
        __syncthreads();
        int4 va0 = *(const int4*)(A + (size_t)(m0 + arow0) * I_ + k0 + cc0);
        int4 va1 = *(const int4*)(A + (size_t)(m0 + arow1) * I_ + k0 + cc0);
        int4 vb  = *(const int4*)(B + (size_t)(n0 + brow) * I_ + k0 + cc0);
        *(int4*)(As + arow0 * 40 + cc0) = va0;
        *(int4*)(As + arow1 * 40 + cc0) = va1;
        *(int4*)(Bs + brow * 40 + cc0) = vb;
        __syncthreads();

        bf16x8 af[4], bf[2];
#pragma unroll
        for (int mi = 0; mi < 4; mi++)
            af[mi] = *(const bf16x8*)(As + (wm + mi * 16 + l15) * 40 + quad * 8);
#pragma unroll
        for (int ni = 0; ni < 2; ni++)
            bf[ni] = *(const bf16x8*)(Bs + (wn + ni * 16 + l15) * 40 + quad * 8);
#pragma unroll
        for (int mi = 0; mi < 4; mi++)
#pragma unroll
            for (int ni = 0; ni < 2; ni++)
                acc[mi][ni] = __builtin_amdgcn_mfma_f32_16x16x32_bf16(
                    af[mi], bf[ni], acc[mi][ni], 0, 0, 0);
    }

#pragma unroll
    for (int mi = 0; mi < 4; mi++)
#pragma unroll
        for (int ni = 0; ni < 2; ni++) {
            int col = n0 + wn + ni * 16 + l15;
#pragma unroll
            for (int r = 0; r < 4; r++) {
                int row = m0 + wm + mi * 16 + quad * 4 + r;
                C[(size_t)row * D_ + col] = acc[mi][ni][r];
            }
        }
}

// ---------------- combine ----------------

__global__ void combine_kernel(const float* __restrict__ y_s,
                               const float* __restrict__ ro,
                               const int* __restrict__ pos_of,
                               const float* __restrict__ pair_w,
                               float* __restrict__ out) {
    int gid = blockIdx.x * 256 + threadIdx.x;   // one float4 each, exact grid
    int t = gid / (D_ / 4);
    int j = (gid % (D_ / 4)) * 4;
    int p0 = pos_of[2 * t], p1 = pos_of[2 * t + 1];
    float w0 = pair_w[p0], w1 = pair_w[p1];
    float4 a = *(const float4*)(y_s + (size_t)t * D_ + j);
    float4 b = *(const float4*)(ro + (size_t)p0 * D_ + j);
    float4 c = *(const float4*)(ro + (size_t)p1 * D_ + j);
    float4 o;
    o.x = a.x + w0 * b.x + w1 * c.x;
    o.y = a.y + w0 * b.y + w1 * c.y;
    o.z = a.z + w0 * b.z + w1 * c.z;
    o.w = a.w + w0 * b.w + w1 * c.w;
    *(float4*)(out + (size_t)t * D_ + j) = o;
}

// ---------------- launch ----------------

extern "C" void kernel_launch(void* const* d_in, const int* in_sizes, int n_in,
                              void* d_out, int out_size, void* d_ws, size_t ws_size,
                              hipStream_t stream) {
    (void)in_sizes; (void)n_in; (void)out_size; (void)ws_size;
    const float* x   = (const float*)d_in[0];
    const float* gw  = (const float*)d_in[2];
    const float* gb  = (const float*)d_in[3];
    const float* w1  = (const float*)d_in[4];
    const float* w2  = (const float*)d_in[5];
    const float* w3  = (const float*)d_in[6];
    const float* w1s = (const float*)d_in[7];
    const float* w2s = (const float*)d_in[8];
    const float* w3s = (const float*)d_in[9];
    float* out = (float*)d_out;

    char* ws = (char*)d_ws;
    size_t off = 0;
    auto alloc = [&](size_t bytes) {
        size_t o = (off + 255) & ~(size_t)255;
        off = o + bytes;
        return (void*)(ws + o);
    };
    unsigned short* xb   = (unsigned short*)alloc((size_t)NTOK * D_ * 2);
    unsigned short* xg   = (unsigned short*)alloc((size_t)NPMAX * D_ * 2);
    unsigned short* w1b  = (unsigned short*)alloc((size_t)E_ * I_ * D_ * 2);
    unsigned short* w3b  = (unsigned short*)alloc((size_t)E_ * I_ * D_ * 2);
    unsigned short* w2b  = (unsigned short*)alloc((size_t)E_ * I_ * D_ * 2);
    unsigned short* w1sb = (unsigned short*)alloc((size_t)I_ * D_ * 2);
    unsigned short* w3sb = (unsigned short*)alloc((size_t)I_ * D_ * 2);
    unsigned short* w2sb = (unsigned short*)alloc((size_t)I_ * D_ * 2);
    unsigned short* acts = (unsigned short*)alloc((size_t)NTOK * I_ * 2);
    unsigned short* actr = (unsigned short*)alloc((size_t)NPMAX * I_ * 2);
    float* ys   = (float*)alloc((size_t)NTOK * D_ * 4);
    float* rout = (float*)alloc((size_t)NPMAX * D_ * 4);
    int*   idx  = (int*)alloc((size_t)NTOK * 2 * 4);
    float* wts  = (float*)alloc((size_t)NTOK * 2 * 4);
    int*   ptok = (int*)alloc((size_t)NPMAX * 4);
    float* pw   = (float*)alloc((size_t)NPMAX * 4);
    int*   posf = (int*)alloc((size_t)NTOK * 2 * 4);
    int*   tls  = (int*)alloc((size_t)MAXTILES * 2 * 4);

    // weights -> bf16 B^T layouts
    tcast_kernel<<<dim3(I_ / 32, D_ / 32, E_), 256, 0, stream>>>(w1, w1b, D_, I_);
    tcast_kernel<<<dim3(I_ / 32, D_ / 32, E_), 256, 0, stream>>>(w3, w3b, D_, I_);
    tcast_kernel<<<dim3(D_ / 32, I_ / 32, E_), 256, 0, stream>>>(w2, w2b, I_, D_);
    tcast_kernel<<<dim3(I_ / 32, D_ / 32, 1), 256, 0, stream>>>(w1s, w1sb, D_, I_);
    tcast_kernel<<<dim3(I_ / 32, D_ / 32, 1), 256, 0, stream>>>(w3s, w3sb, D_, I_);
    tcast_kernel<<<dim3(D_ / 32, I_ / 32, 1), 256, 0, stream>>>(w2s, w2sb, I_, D_);

    cast_x_kernel<<<NTOK * D_ / 4 / 256, 256, 0, stream>>>(x, xb);
    gate_topk_kernel<<<NTOK / 4, 256, 0, stream>>>(x, gw, gb, idx, wts);
    route_build_kernel<<<1, 256, 0, stream>>>(idx, wts, ptok, pw, posf, tls);
    gather_kernel<<<NPMAX * (D_ / 8) / 256, 256, 0, stream>>>(xb, ptok, xg);

    gemm_act_kernel<<<dim3(I_ / 64, NSHT + MAXTILES), 256, 0, stream>>>(
        xb, xg, w1sb, w3sb, w1b, w3b, tls, acts, actr);
    gemm_out_kernel<<<dim3(D_ / 64, NSHT + MAXTILES), 256, 0, stream>>>(
        acts, actr, w2sb, w2b, tls, ys, rout);
    combine_kernel<<<NTOK * (D_ / 4) / 256, 256, 0, stream>>>(ys, rout, posf, pw, out);
}

// Round 2
// 474.113 us; speedup vs baseline: 1.0954x; 1.0954x over previous
//
#include <hip/hip_runtime.h>

// DeepSeek MoE (N=2048, D=768, I=3072, E=8, K=2 + shared expert), fp32 in/out,
// bf16 MFMA compute. Sparse routed experts via counting-sort + grouped GEMM.
//
// R2: m97-style global_load_lds(16B) staging in both GEMMs (unpadded LDS,
//     wave-uniform base + lane*16 layout); coalesced 64x64 transpose-cast
//     merged into 2 launches.

#define D_ 768
#define I_ 3072
#define E_ 8
#define NTOK 2048
#define NPMAX 5120          // 4096 pairs + worst-case 128-padding per expert
#define MAXTILES 40         // sum ceil(c_e/128) <= 39
#define NSHT 16             // shared-expert M tiles: 2048/128

typedef __bf16 bf16x8 __attribute__((ext_vector_type(8)));
typedef float floatx4 __attribute__((ext_vector_type(4)));

#define GLOAD_LDS16(g, l) __builtin_amdgcn_global_load_lds( \
    (const __attribute__((address_space(1))) void*)(g),     \
    (__attribute__((address_space(3))) void*)(l), 16, 0, 0)

__device__ __forceinline__ unsigned short f2b(float f) {
    unsigned int u = __float_as_uint(f);
    u += 0x7fffu + ((u >> 16) & 1u);          // RNE to bf16
    return (unsigned short)(u >> 16);
}

// ---------------- cast / transpose ----------------
// 64x64 tile: coalesced float4 reads, coalesced 16B bf16 writes (128B/8 lanes).

template <int R, int C>
__device__ __forceinline__ void tbody(const float* __restrict__ s,
                                      unsigned short* __restrict__ d) {
    __shared__ float t[64][65];
    int c0 = blockIdx.x * 64, r0 = blockIdx.y * 64;
    int tid = threadIdx.x;
#pragma unroll
    for (int j = 0; j < 4; j++) {
        int slot = tid + j * 256;            // 0..1023
        int r = slot >> 4;                   // 0..63
        int c4 = (slot & 15) * 4;
        float4 v = *(const float4*)(s + (size_t)(r0 + r) * C + c0 + c4);
        t[r][c4] = v.x; t[r][c4 + 1] = v.y; t[r][c4 + 2] = v.z; t[r][c4 + 3] = v.w;
    }
    __syncthreads();
#pragma unroll
    for (int j = 0; j < 2; j++) {
        int slot = tid + j * 256;            // 0..511
        int c = slot >> 3;                   // 0..63 (out row = C index)
        int rs = (slot & 7) * 8;             // out col chunk (R index)
        unsigned short o[8];
#pragma unroll
        for (int i = 0; i < 8; i++) o[i] = f2b(t[rs + i][c]);
        *(int4*)(d + (size_t)(c0 + c) * R + r0 + rs) = *(const int4*)o;
    }
}

// z: 0..7 -> w1[e], 8..15 -> w3[e], 16 -> w1s, 17 -> w3s   (src [D][I])
__global__ void tcastDI_kernel(const float* __restrict__ w1,
                               const float* __restrict__ w3,
                               const float* __restrict__ w1s,
                               const float* __restrict__ w3s,
                               unsigned short* __restrict__ w1b,
                               unsigned short* __restrict__ w3b,
                               unsigned short* __restrict__ w1sb,
                               unsigned short* __restrict__ w3sb) {
    int z = blockIdx.z;
    const float* s;
    unsigned short* d;
    if (z < 8)        { s = w1 + (size_t)z * D_ * I_;       d = w1b + (size_t)z * D_ * I_; }
    else if (z < 16)  { s = w3 + (size_t)(z - 8) * D_ * I_; d = w3b + (size_t)(z - 8) * D_ * I_; }
    else if (z == 16) { s = w1s; d = w1sb; }
    else              { s = w3s; d = w3sb; }
    tbody<D_, I_>(s, d);
}

// z: 0..7 -> w2[e], 8 -> w2s   (src [I][D])
__global__ void tcastID_kernel(const float* __restrict__ w2,
                               const float* __restrict__ w2s,
                               unsigned short* __restrict__ w2b,
                               unsigned short* __restrict__ w2sb) {
    int z = blockIdx.z;
    const float* s;
    unsigned short* d;
    if (z < 8) { s = w2 + (size_t)z * I_ * D_; d = w2b + (size_t)z * I_ * D_; }
    else       { s = w2s; d = w2sb; }
    tbody<I_, D_>(s, d);
}

__global__ void cast_x_kernel(const float* __restrict__ x,
                              unsigned short* __restrict__ xb) {
    int gid = blockIdx.x * 256 + threadIdx.x;   // one float4 each, exact grid
    float4 v = *(const float4*)(x + (size_t)gid * 4);
    ushort4 o;
    o.x = f2b(v.x); o.y = f2b(v.y); o.z = f2b(v.z); o.w = f2b(v.w);
    *(ushort4*)(xb + (size_t)gid * 4) = o;
}

// ---------------- gating ----------------

__global__ void gate_topk_kernel(const float* __restrict__ x,
                                 const float* __restrict__ gw,
                                 const float* __restrict__ gb,
                                 int* __restrict__ idx, float* __restrict__ wts) {
    int t = blockIdx.x * 4 + (threadIdx.x >> 6);   // one wave per token
    int lane = threadIdx.x & 63;
    float z[E_];
#pragma unroll
    for (int e = 0; e < E_; e++) z[e] = 0.f;
    const float* xr = x + (size_t)t * D_;
    for (int j = lane; j < D_; j += 64) {
        float xv = xr[j];
        const float* g = gw + (size_t)j * E_;
#pragma unroll
        for (int e = 0; e < E_; e++) z[e] += xv * g[e];
    }
#pragma unroll
    for (int off = 32; off > 0; off >>= 1)
#pragma unroll
        for (int e = 0; e < E_; e++) z[e] += __shfl_down(z[e], off, 64);
    if (lane == 0) {
        float s[E_], r[E_];
#pragma unroll
        for (int e = 0; e < E_; e++) {
            float zz = z[e];
            float sp = zz > 0.f ? zz + log1pf(expf(-zz)) : log1pf(expf(zz));
            s[e] = sqrtf(sp);
            r[e] = s[e] + gb[e];   // bias only for selection
        }
        int i0 = 0;
        for (int e = 1; e < E_; e++) if (r[e] > r[i0]) i0 = e;   // ties -> low idx
        int i1 = (i0 == 0) ? 1 : 0;
        for (int e = 0; e < E_; e++) if (e != i0 && r[e] > r[i1]) i1 = e;
        float w0 = s[i0], w1 = s[i1];
        float inv = 1.f / fmaxf(w0 + w1, 1e-6f);
        idx[2 * t] = i0; idx[2 * t + 1] = i1;
        wts[2 * t] = w0 * inv; wts[2 * t + 1] = w1 * inv;
    }
}

// ---------------- routing build (single block) ----------------

__global__ void route_build_kernel(const int* __restrict__ idx,
                                   const float* __restrict__ wts,
                                   int* __restrict__ pair_token,
                                   float* __restrict__ pair_w,
                                   int* __restrict__ pos_of,
                                   int* __restrict__ tiles) {
    __shared__ int cnt[E_], seg[E_], cur[E_];
    int tid = threadIdx.x;
    if (tid < E_) { cnt[tid] = 0; cur[tid] = 0; }
    __syncthreads();
    for (int p = tid; p < NTOK * 2; p += 256) atomicAdd(&cnt[idx[p]], 1);
    __syncthreads();
    if (tid == 0) {
        int off = 0, nt = 0;
        for (int e = 0; e < E_; e++) {
            seg[e] = off;
            int te = (cnt[e] + 127) >> 7;
            for (int j = 0; j < te; j++) {
                tiles[nt * 2] = e; tiles[nt * 2 + 1] = off + j * 128; nt++;
            }
            off += te * 128;
        }
        for (; nt < MAXTILES; nt++) { tiles[nt * 2] = -1; tiles[nt * 2 + 1] = 0; }
    }
    for (int p = tid; p < NPMAX; p += 256) pair_token[p] = -1;
    __syncthreads();
    for (int p = tid; p < NTOK * 2; p += 256) {
        int e = idx[p];
        int r = atomicAdd(&cur[e], 1);
        int pos = seg[e] + r;
        pair_token[pos] = p >> 1;
        pair_w[pos] = wts[p];
        pos_of[p] = pos;
    }
}

__global__ void gather_kernel(const unsigned short* __restrict__ xb,
                              const int* __restrict__ pair_token,
                              unsigned short* __restrict__ xg) {
    int gid = blockIdx.x * 256 + threadIdx.x;   // 8 bf16 each, exact grid
    int p = gid / (D_ / 8);
    int j = (gid % (D_ / 8)) * 8;
    int t = pair_token[p];
    int4 v = make_int4(0, 0, 0, 0);             // pad rows -> zeros
    if (t >= 0) v = *(const int4*)(xb + (size_t)t * D_ + j);
    *(int4*)(xg + (size_t)p * D_ + j) = v;
}

// ---------------- GEMM 1: fused gate/up + activation ----------------
// BM=128, BN=64(x2 weights), BK=32; async global->LDS staging, unpadded LDS.
// A: [rows][768] bf16. B^T: [I][768] bf16. Out: act bf16 [rows][I].

__launch_bounds__(256)
__global__ void gemm_act_kernel(const unsigned short* __restrict__ xb,
                                const unsigned short* __restrict__ xg,
                                const unsigned short* __restrict__ w1sb,
                                const unsigned short* __restrict__ w3sb,
                                const unsigned short* __restrict__ w1b,
                                const unsigned short* __restrict__ w3b,
                                const int* __restrict__ tiles,
                                unsigned short* __restrict__ act_s,
                                unsigned short* __restrict__ act_r) {
    __shared__ __align__(16) unsigned short As[128 * 32];
    __shared__ __align__(16) unsigned short Bs1[64 * 32];
    __shared__ __align__(16) unsigned short Bs3[64 * 32];

    int mt = blockIdx.y;
    const unsigned short *A, *B1, *B3;
    unsigned short* C;
    int m0;
    if (mt < NSHT) {
        A = xb; B1 = w1sb; B3 = w3sb; C = act_s; m0 = mt * 128;
    } else {
        int e = tiles[(mt - NSHT) * 2];
        if (e < 0) return;
        m0 = tiles[(mt - NSHT) * 2 + 1];
        A = xg; B1 = w1b + (size_t)e * I_ * D_; B3 = w3b + (size_t)e * I_ * D_;
        C = act_r;
    }
    int n0 = blockIdx.x * 64;
    int tid = threadIdx.x;
    int lane = tid & 63, wave = tid >> 6;
    int wm = (wave & 1) * 64, wn = (wave >> 1) * 32;
    int l15 = lane & 15, quad = lane >> 4;
    int l4 = lane >> 2, c8 = (lane & 3) * 8;   // staging: lane -> (row l4, col c8)

    const unsigned short* Ap0 = A + (size_t)(m0 + wave * 16 + l4) * D_ + c8;
    const unsigned short* Ap1 = Ap0 + (size_t)64 * D_;
    const unsigned short* B1p = B1 + (size_t)(n0 + wave * 16 + l4) * D_ + c8;
    const unsigned short* B3p = B3 + (size_t)(n0 + wave * 16 + l4) * D_ + c8;
    unsigned short* AsW0 = As + wave * 16 * 32;          // wave-uniform LDS bases
    unsigned short* AsW1 = As + (64 + wave * 16) * 32;
    unsigned short* Bs1W = Bs1 + wave * 16 * 32;
    unsigned short* Bs3W = Bs3 + wave * 16 * 32;

    floatx4 acc1[4][2] = {}; floatx4 acc3[4][2] = {};

    for (int k0 = 0; k0 < D_; k0 += 32) {
        __syncthreads();
        GLOAD_LDS16(Ap0 + k0, AsW0);
        GLOAD_LDS16(Ap1 + k0, AsW1);
        GLOAD_LDS16(B1p + k0, Bs1W);
        GLOAD_LDS16(B3p + k0, Bs3W);
        __syncthreads();

        bf16x8 af[4], b1f[2], b3f[2];
#pragma unroll
        for (int mi = 0; mi < 4; mi++)
            af[mi] = *(const bf16x8*)(As + (wm + mi * 16 + l15) * 32 + quad * 8);
#pragma unroll
        for (int ni = 0; ni < 2; ni++) {
            b1f[ni] = *(const bf16x8*)(Bs1 + (wn + ni * 16 + l15) * 32 + quad * 8);
            b3f[ni] = *(const bf16x8*)(Bs3 + (wn + ni * 16 + l15) * 32 + quad * 8);
        }
#pragma unroll
        for (int mi = 0; mi < 4; mi++)
#pragma unroll
            for (int ni = 0; ni < 2; ni++) {
                acc1[mi][ni] = __builtin_amdgcn_mfma_f32_16x16x32_bf16(
                    af[mi], b1f[ni], acc1[mi][ni], 0, 0, 0);
                acc3[mi][ni] = __builtin_amdgcn_mfma_f32_16x16x32_bf16(
                    af[mi], b3f[ni], acc3[mi][ni], 0, 0, 0);
            }
    }

#pragma unroll
    for (int mi = 0; mi < 4; mi++)
#pragma unroll
        for (int ni = 0; ni < 2; ni++) {
            int col = n0 + wn + ni * 16 + l15;
#pragma unroll
            for (int r = 0; r < 4; r++) {
                int row = m0 + wm + mi * 16 + quad * 4 + r;   // C/D: row=quad*4+r
                float g = fminf(acc1[mi][ni][r], 10.f);
                float u = fminf(fmaxf(acc3[mi][ni][r], -10.f), 10.f);
                float a = g / (1.f + __expf(-g)) * u;          // silu(g)*u
                C[(size_t)row * I_ + col] = f2b(a);
            }
        }
}

// ---------------- GEMM 2: act @ W2 ----------------
// A: act bf16 [rows][3072]. B^T: w2b [768][3072] bf16. Out: fp32 [rows][768].

__launch_bounds__(256)
__global__ void gemm_out_kernel(const unsigned short* __restrict__ act_s,
                                const unsigned short* __restrict__ act_r,
                                const unsigned short* __restrict__ w2sb,
                                const unsigned short* __restrict__ w2b,
                                const int* __restrict__ tiles,
                                float* __restrict__ y_s, float* __restrict__ ro) {
    __shared__ __align__(16) unsigned short As[128 * 32];
    __shared__ __align__(16) unsigned short Bs[64 * 32];

    int mt = blockIdx.y;
    const unsigned short *A, *B;
    float* C;
    int m0;
    if (mt < NSHT) {
        A = act_s; B = w2sb; C = y_s; m0 = mt * 128;
    } else {
        int e = tiles[(mt - NSHT) * 2];
        if (e < 0) return;
        m0 = tiles[(mt - NSHT) * 2 + 1];
        A = act_r; B = w2b + (size_t)e * I_ * D_; C = ro;
    }
    int n0 = blockIdx.x * 64;
    int tid = threadIdx.x;
    int lane = tid & 63, wave = tid >> 6;
    int wm = (wave & 1) * 64, wn = (wave >> 1) * 32;
    int l15 = lane & 15, quad = lane >> 4;
    int l4 = lane >> 2, c8 = (lane & 3) * 8;

    const unsigned short* Ap0 = A + (size_t)(m0 + wave * 16 + l4) * I_ + c8;
    const unsigned short* Ap1 = Ap0 + (size_t)64 * I_;
    const unsigned short* Bp  = B + (size_t)(n0 + wave * 16 + l4) * I_ + c8;
    unsigned short* AsW0 = As + wave * 16 * 32;
    unsigned short* AsW1 = As + (64 + wave * 16) * 32;
    unsigned short* BsW  = Bs + wave * 16 * 32;

    floatx4 acc[4][2] = {};

    for (int k0 = 0; k0 < I_; k0 += 32) {
        __syncthreads();
        GLOAD_LDS16(Ap0 + k0, AsW0);
        GLOAD_LDS16(Ap1 + k0, AsW1);
        GLOAD_LDS16(Bp + k0, BsW);
        __syncthreads();

        bf16x8 af[4], bf[2];
#pragma unroll
        for (int mi = 0; mi < 4; mi++)
            af[mi] = *(const bf16x8*)(As + (wm + mi * 16 + l15) * 32 + quad * 8);
#pragma unroll
        for (int ni = 0; ni < 2; ni++)
            bf[ni] = *(const bf16x8*)(Bs + (wn + ni * 16 + l15) * 32 + quad * 8);
#pragma unroll
        for (int mi = 0; mi < 4; mi++)
#pragma unroll
            for (int ni = 0; ni < 2; ni++)
                acc[mi][ni] = __builtin_amdgcn_mfma_f32_16x16x32_bf16(
                    af[mi], bf[ni], acc[mi][ni], 0, 0, 0);
    }

#pragma unroll
    for (int mi = 0; mi < 4; mi++)
#pragma unroll
        for (int ni = 0; ni < 2; ni++) {
            int col = n0 + wn + ni * 16 + l15;
#pragma unroll
            for (int r = 0; r < 4; r++) {
                int row = m0 + wm + mi * 16 + quad * 4 + r;
                C[(size_t)row * D_ + col] = acc[mi][ni][r];
            }
        }
}

// ---------------- combine ----------------

__global__ void combine_kernel(const float* __restrict__ y_s,
                               const float* __restrict__ ro,
                               const int* __restrict__ pos_of,
                               const float* __restrict__ pair_w,
                               float* __restrict__ out) {
    int gid = blockIdx.x * 256 + threadIdx.x;   // one float4 each, exact grid
    int t = gid / (D_ / 4);
    int j = (gid % (D_ / 4)) * 4;
    int p0 = pos_of[2 * t], p1 = pos_of[2 * t + 1];
    float w0 = pair_w[p0], w1 = pair_w[p1];
    float4 a = *(const float4*)(y_s + (size_t)t * D_ + j);
    float4 b = *(const float4*)(ro + (size_t)p0 * D_ + j);
    float4 c = *(const float4*)(ro + (size_t)p1 * D_ + j);
    float4 o;
    o.x = a.x + w0 * b.x + w1 * c.x;
    o.y = a.y + w0 * b.y + w1 * c.y;
    o.z = a.z + w0 * b.z + w1 * c.z;
    o.w = a.w + w0 * b.w + w1 * c.w;
    *(float4*)(out + (size_t)t * D_ + j) = o;
}

// ---------------- launch ----------------

extern "C" void kernel_launch(void* const* d_in, const int* in_sizes, int n_in,
                              void* d_out, int out_size, void* d_ws, size_t ws_size,
                              hipStream_t stream) {
    (void)in_sizes; (void)n_in; (void)out_size; (void)ws_size;
    const float* x   = (const float*)d_in[0];
    const float* gw  = (const float*)d_in[2];
    const float* gb  = (const float*)d_in[3];
    const float* w1  = (const float*)d_in[4];
    const float* w2  = (const float*)d_in[5];
    const float* w3  = (const float*)d_in[6];
    const float* w1s = (const float*)d_in[7];
    const float* w2s = (const float*)d_in[8];
    const float* w3s = (const float*)d_in[9];
    float* out = (float*)d_out;

    char* ws = (char*)d_ws;
    size_t off = 0;
    auto alloc = [&](size_t bytes) {
        size_t o = (off + 255) & ~(size_t)255;
        off = o + bytes;
        return (void*)(ws + o);
    };
    unsigned short* xb   = (unsigned short*)alloc((size_t)NTOK * D_ * 2);
    unsigned short* xg   = (unsigned short*)alloc((size_t)NPMAX * D_ * 2);
    unsigned short* w1b  = (unsigned short*)alloc((size_t)E_ * I_ * D_ * 2);
    unsigned short* w3b  = (unsigned short*)alloc((size_t)E_ * I_ * D_ * 2);
    unsigned short* w2b  = (unsigned short*)alloc((size_t)E_ * I_ * D_ * 2);
    unsigned short* w1sb = (unsigned short*)alloc((size_t)I_ * D_ * 2);
    unsigned short* w3sb = (unsigned short*)alloc((size_t)I_ * D_ * 2);
    unsigned short* w2sb = (unsigned short*)alloc((size_t)I_ * D_ * 2);
    unsigned short* acts = (unsigned short*)alloc((size_t)NTOK * I_ * 2);
    unsigned short* actr = (unsigned short*)alloc((size_t)NPMAX * I_ * 2);
    float* ys   = (float*)alloc((size_t)NTOK * D_ * 4);
    float* rout = (float*)alloc((size_t)NPMAX * D_ * 4);
    int*   idx  = (int*)alloc((size_t)NTOK * 2 * 4);
    float* wts  = (float*)alloc((size_t)NTOK * 2 * 4);
    int*   ptok = (int*)alloc((size_t)NPMAX * 4);
    float* pw   = (float*)alloc((size_t)NPMAX * 4);
    int*   posf = (int*)alloc((size_t)NTOK * 2 * 4);
    int*   tls  = (int*)alloc((size_t)MAXTILES * 2 * 4);

    // weights -> bf16 B^T layouts (coalesced 64x64 transpose, 2 launches)
    tcastDI_kernel<<<dim3(I_ / 64, D_ / 64, 18), 256, 0, stream>>>(
        w1, w3, w1s, w3s, w1b, w3b, w1sb, w3sb);
    tcastID_kernel<<<dim3(D_ / 64, I_ / 64, 9), 256, 0, stream>>>(
        w2, w2s, w2b, w2sb);

    cast_x_kernel<<<NTOK * D_ / 4 / 256, 256, 0, stream>>>(x, xb);
    gate_topk_kernel<<<NTOK / 4, 256, 0, stream>>>(x, gw, gb, idx, wts);
    route_build_kernel<<<1, 256, 0, stream>>>(idx, wts, ptok, pw, posf, tls);
    gather_kernel<<<NPMAX * (D_ / 8) / 256, 256, 0, stream>>>(xb, ptok, xg);

    gemm_act_kernel<<<dim3(I_ / 64, NSHT + MAXTILES), 256, 0, stream>>>(
        xb, xg, w1sb, w3sb, w1b, w3b, tls, acts, actr);
    gemm_out_kernel<<<dim3(D_ / 64, NSHT + MAXTILES), 256, 0, stream>>>(
        acts, actr, w2sb, w2b, tls, ys, rout);
    combine_kernel<<<NTOK * (D_ / 4) / 256, 256, 0, stream>>>(ys, rout, posf, pw, out);
}